// Round 1
// baseline (4199.885 us; speedup 1.0000x reference)
//
#include <hip/hip_runtime.h>

// Memory-network read: cosine addressing + softmax(T=0.5) + hard_shrink_relu
// + L1 renorm + weighted read.  x:[16,2048,64] f32, memories:[4096,64] f32.
// out = concat(read [32768*64], weight [32768*4096]) f32.
//
// Structure: one wave (64 lanes) per row of x.  Lane l owns memories
// m = 64k + l (k=0..63): logits, softmax weights all live in registers
// (64/lane); reductions via __shfl_xor.  Read-GEMM uses a wave-uniform
// __ballot skip over zero weights (hard-shrink makes weights sparse).

#define NM 4096
#define HD 64
#define NROWS 32768  // 16*2048

// ---- kernel 1: inverse L2 norms of memories -> d_ws (4096 floats) ----
__global__ __launch_bounds__(256) void prep_invm(const float* __restrict__ mem,
                                                 float* __restrict__ invm) {
    const int wave = threadIdx.x >> 6;
    const int lane = threadIdx.x & 63;
    const int row  = blockIdx.x * 4 + wave;
    float v = mem[row * HD + lane];
    float s = v * v;
#pragma unroll
    for (int o = 32; o > 0; o >>= 1) s += __shfl_xor(s, o, 64);
    if (lane == 0) invm[row] = 1.0f / fmaxf(sqrtf(s), 1e-12f);
}

// ---- kernel 2: fused addressing + softmax + shrink + L1 + read ----
__global__ __launch_bounds__(256) void fused(const float* __restrict__ x,
                                             const float* __restrict__ mem,
                                             const float* __restrict__ invm,
                                             float* __restrict__ out_read,
                                             float* __restrict__ out_w) {
    const int wave = threadIdx.x >> 6;
    const int lane = threadIdx.x & 63;
    const long g = (long)blockIdx.x * 4 + wave;  // global row id < 32768

    // --- normalize x row (norm via shuffle reduce; row broadcast-loaded) ---
    const float* xrow = x + g * HD;
    float xl = xrow[lane];
    float s = xl * xl;
#pragma unroll
    for (int o = 32; o > 0; o >>= 1) s += __shfl_xor(s, o, 64);
    const float invx = 1.0f / fmaxf(sqrtf(s), 1e-12f);

    float xn[HD];  // normalized x row, replicated per lane (static indexing)
#pragma unroll
    for (int j = 0; j < 16; j++) {
        float4 v = ((const float4*)xrow)[j];
        xn[4 * j + 0] = v.x * invx;
        xn[4 * j + 1] = v.y * invx;
        xn[4 * j + 2] = v.z * invx;
        xn[4 * j + 3] = v.w * invx;
    }

    // --- phase 1: logits/T for m = 64k + lane, k = 0..63 ---
    float lg[64];
#pragma unroll
    for (int k = 0; k < 64; k++) {
        const int m = 64 * k + lane;
        const float4* mr = (const float4*)(mem + (long)m * HD);
        float acc = 0.0f;
#pragma unroll
        for (int j = 0; j < 16; j++) {
            float4 v = mr[j];
            acc = fmaf(xn[4 * j + 0], v.x, acc);
            acc = fmaf(xn[4 * j + 1], v.y, acc);
            acc = fmaf(xn[4 * j + 2], v.z, acc);
            acc = fmaf(xn[4 * j + 3], v.w, acc);
        }
        lg[k] = acc * invm[m] * 2.0f;  // cosine sim / T, T = 0.5
    }

    // --- softmax (max, exp, sum) ---
    float mx = lg[0];
#pragma unroll
    for (int k = 1; k < 64; k++) mx = fmaxf(mx, lg[k]);
#pragma unroll
    for (int o = 32; o > 0; o >>= 1) mx = fmaxf(mx, __shfl_xor(mx, o, 64));

    float se = 0.0f;
#pragma unroll
    for (int k = 0; k < 64; k++) {
        lg[k] = __expf(lg[k] - mx);
        se += lg[k];
    }
#pragma unroll
    for (int o = 32; o > 0; o >>= 1) se += __shfl_xor(se, o, 64);
    const float rS = 1.0f / se;

    // --- hard_shrink_relu + L1 ---
    float l1 = 0.0f;
#pragma unroll
    for (int k = 0; k < 64; k++) {
        float w  = lg[k] * rS;
        float d  = w - 0.0025f;
        float rd = fmaxf(d, 0.0f);
        float sh = (rd > 0.0f) ? __fdividef(rd * w, fabsf(d) + 1e-12f) : 0.0f;
        lg[k] = sh;
        l1 += sh;
    }
#pragma unroll
    for (int o = 32; o > 0; o >>= 1) l1 += __shfl_xor(l1, o, 64);
    const float rL = 1.0f / fmaxf(l1, 1e-12f);

    // --- write weights (coalesced: lane l -> m = 64k + l) ---
    float* wrow = out_w + g * (long)NM;
#pragma unroll
    for (int k = 0; k < 64; k++) {
        lg[k] *= rL;
        wrow[64 * k + lane] = lg[k];
    }

    // --- read = weight @ memories; lane l owns output dim d = l.
    //     Wave-uniform ballot skips zero weights (shrink sparsity). ---
    float acc = 0.0f;
#pragma unroll
    for (int k = 0; k < 64; k++) {
        unsigned long long mask = __ballot(lg[k] != 0.0f);
        while (mask) {
            const int j = __ffsll(mask) - 1;
            mask &= (mask - 1);
            const float wv = __shfl(lg[k], j, 64);
            acc = fmaf(wv, mem[(long)(64 * k + j) * HD + lane], acc);
        }
    }
    out_read[g * HD + lane] = acc;
}

extern "C" void kernel_launch(void* const* d_in, const int* in_sizes, int n_in,
                              void* d_out, int out_size, void* d_ws, size_t ws_size,
                              hipStream_t stream) {
    const float* x   = (const float*)d_in[0];
    const float* mem = (const float*)d_in[1];
    float* invm      = (float*)d_ws;              // 4096 floats = 16 KB scratch
    float* out       = (float*)d_out;
    float* out_read  = out;                       // [32768*64]
    float* out_w     = out + (long)NROWS * HD;    // [32768*4096]

    prep_invm<<<NM / 4, 256, 0, stream>>>(mem, invm);
    fused<<<NROWS / 4, 256, 0, stream>>>(x, mem, invm, out_read, out_w);
}

// Round 2
// 872.668 us; speedup vs baseline: 4.8127x; 4.8127x over previous
//
#include <hip/hip_runtime.h>

// Two-pass memory-network read.
//   K0a prep_m : m-hat transposed  mT[64][4096] -> d_ws (1 MB)
//   K0b prep_x : x-hat * 2 (1/T folded)         -> out_read region (8.4 MB, temp)
//   K1  sgemm  : logits[32768][4096] = xhat2 @ mT -> out_w region (temp, fp32)
//   K2  finish : per-row softmax + hard-shrink + L1-renorm, rewrites out_w
//                in place, sparse read-GEMM -> out_read (overwrites x-hat).
// All global access coalesced; logits spill through HBM (one extra 537 MB
// read vs fused, but removes the 34 TB LDS-traffic wall of the fused form).

#define NM 4096
#define HD 64
#define NROWS 32768  // 16*2048

// ---- K0a: normalized memories, transposed: mT[k][n] = mem[n][k]/||mem[n]|| ----
__global__ __launch_bounds__(256) void prep_m(const float* __restrict__ mem,
                                              float* __restrict__ mT) {
    const int wave = threadIdx.x >> 6, lane = threadIdx.x & 63;
    const int row  = blockIdx.x * 4 + wave;
    float v = mem[row * HD + lane];
    float s = v * v;
#pragma unroll
    for (int o = 32; o; o >>= 1) s += __shfl_xor(s, o, 64);
    const float inv = 1.0f / fmaxf(sqrtf(s), 1e-12f);
    mT[lane * NM + row] = v * inv;   // scattered, but only 1 MB total
}

// ---- K0b: x-hat scaled by 2 (= 1/T), written to out_read as scratch ----
__global__ __launch_bounds__(256) void prep_x(const float* __restrict__ x,
                                              float* __restrict__ xn) {
    const int wave = threadIdx.x >> 6, lane = threadIdx.x & 63;
    const long row = (long)blockIdx.x * 4 + wave;
    float v = x[row * HD + lane];
    float s = v * v;
#pragma unroll
    for (int o = 32; o; o >>= 1) s += __shfl_xor(s, o, 64);
    const float inv = 2.0f / fmaxf(sqrtf(s), 1e-12f);
    xn[row * HD + lane] = v * inv;
}

// ---- K1: 128x128-tile fp32 SGEMM, K=64 fully staged in LDS ----
__global__ __launch_bounds__(256) void sgemm_logits(const float* __restrict__ xn,
                                                    const float* __restrict__ mT,
                                                    float* __restrict__ out_w) {
    __shared__ float As[HD][128];  // [k][m]  (transposed x-tile)
    __shared__ float Bs[HD][128];  // [k][n]
    const int t  = threadIdx.x;
    const int tx = t & 15, ty = t >> 4;
    const int n0 = blockIdx.x * 128;
    const int m0 = blockIdx.y * 128;

    // stage A: 128 rows x 64 k, transpose into As
#pragma unroll
    for (int i = 0; i < 8; i++) {
        int idx = t + i * 256;          // 0..2047 float4s
        int m   = idx >> 4;
        int kb  = (idx & 15) << 2;
        float4 v = *(const float4*)(xn + (long)(m0 + m) * HD + kb);
        As[kb + 0][m] = v.x; As[kb + 1][m] = v.y;
        As[kb + 2][m] = v.z; As[kb + 3][m] = v.w;
    }
    // stage B: 64 k-rows x 128 n (already transposed in mT)
#pragma unroll
    for (int i = 0; i < 8; i++) {
        int idx = t + i * 256;
        int k   = idx >> 5;
        int nb  = (idx & 31) << 2;
        *(float4*)&Bs[k][nb] = *(const float4*)(mT + (long)k * NM + n0 + nb);
    }
    __syncthreads();

    float acc[8][8];
#pragma unroll
    for (int i = 0; i < 8; i++)
#pragma unroll
        for (int j = 0; j < 8; j++) acc[i][j] = 0.0f;

#pragma unroll 8
    for (int k = 0; k < HD; k++) {
        float4 a0 = *(const float4*)&As[k][ty * 4];
        float4 a1 = *(const float4*)&As[k][64 + ty * 4];
        float4 b0 = *(const float4*)&Bs[k][tx * 4];
        float4 b1 = *(const float4*)&Bs[k][64 + tx * 4];
        float a[8] = {a0.x, a0.y, a0.z, a0.w, a1.x, a1.y, a1.z, a1.w};
        float b[8] = {b0.x, b0.y, b0.z, b0.w, b1.x, b1.y, b1.z, b1.w};
#pragma unroll
        for (int i = 0; i < 8; i++)
#pragma unroll
            for (int j = 0; j < 8; j++)
                acc[i][j] = fmaf(a[i], b[j], acc[i][j]);
    }

#pragma unroll
    for (int ig = 0; ig < 2; ig++)
#pragma unroll
        for (int ii = 0; ii < 4; ii++) {
            const long m = m0 + ig * 64 + ty * 4 + ii;
            float* wr = out_w + m * NM + n0;
            const int i = ig * 4 + ii;
            *(float4*)(wr + tx * 4) =
                make_float4(acc[i][0], acc[i][1], acc[i][2], acc[i][3]);
            *(float4*)(wr + 64 + tx * 4) =
                make_float4(acc[i][4], acc[i][5], acc[i][6], acc[i][7]);
        }
}

// ---- K2: softmax + hard_shrink_relu + L1 renorm + sparse read-GEMM ----
__global__ __launch_bounds__(256) void finish(float* __restrict__ out_w,
                                              const float* __restrict__ mem,
                                              float* __restrict__ out_read) {
    const int wave = threadIdx.x >> 6, lane = threadIdx.x & 63;
    const long row = (long)blockIdx.x * 4 + wave;
    float* wrow = out_w + row * (long)NM;

    // lane owns memories {c*256 + 4*lane .. +3}, c = 0..15
    float4 lw[16];
#pragma unroll
    for (int c = 0; c < 16; c++)
        lw[c] = *(const float4*)(wrow + c * 256 + lane * 4);

    float mx = -1e30f;
#pragma unroll
    for (int c = 0; c < 16; c++)
        mx = fmaxf(mx, fmaxf(fmaxf(lw[c].x, lw[c].y), fmaxf(lw[c].z, lw[c].w)));
#pragma unroll
    for (int o = 32; o; o >>= 1) mx = fmaxf(mx, __shfl_xor(mx, o, 64));

    float se = 0.0f;
#pragma unroll
    for (int c = 0; c < 16; c++) {
        lw[c].x = __expf(lw[c].x - mx); se += lw[c].x;
        lw[c].y = __expf(lw[c].y - mx); se += lw[c].y;
        lw[c].z = __expf(lw[c].z - mx); se += lw[c].z;
        lw[c].w = __expf(lw[c].w - mx); se += lw[c].w;
    }
#pragma unroll
    for (int o = 32; o; o >>= 1) se += __shfl_xor(se, o, 64);
    const float rS = 1.0f / se;

    float l1 = 0.0f;
#pragma unroll
    for (int c = 0; c < 16; c++) {
        float* e = &lw[c].x;
#pragma unroll
        for (int q = 0; q < 4; q++) {
            float w  = e[q] * rS;
            float d  = w - 0.0025f;
            float sh = __fdividef(fmaxf(d, 0.0f) * w, fabsf(d) + 1e-12f);
            e[q] = sh;
            l1  += sh;
        }
    }
#pragma unroll
    for (int o = 32; o; o >>= 1) l1 += __shfl_xor(l1, o, 64);
    const float rL = 1.0f / fmaxf(l1, 1e-12f);

    float racc = 0.0f;
#pragma unroll
    for (int c = 0; c < 16; c++) {
        float4 wv;
        wv.x = lw[c].x * rL; wv.y = lw[c].y * rL;
        wv.z = lw[c].z * rL; wv.w = lw[c].w * rL;
        *(float4*)(wrow + c * 256 + lane * 4) = wv;

        // sparse read-GEMM: wave-uniform skip of all-zero lanes
        const bool nz = (wv.x != 0.0f) | (wv.y != 0.0f) |
                        (wv.z != 0.0f) | (wv.w != 0.0f);
        unsigned long long mask = __ballot(nz);
        while (mask) {
            const int j = __ffsll((long long)mask) - 1;
            mask &= (mask - 1);
            float w0 = __shfl(wv.x, j, 64), w1 = __shfl(wv.y, j, 64);
            float w2 = __shfl(wv.z, j, 64), w3 = __shfl(wv.w, j, 64);
            const long mbase = (long)(c * 256 + 4 * j) * HD + lane;
            racc = fmaf(w0, mem[mbase + 0 * HD], racc);
            racc = fmaf(w1, mem[mbase + 1 * HD], racc);
            racc = fmaf(w2, mem[mbase + 2 * HD], racc);
            racc = fmaf(w3, mem[mbase + 3 * HD], racc);
        }
    }
    out_read[row * HD + lane] = racc;
}

extern "C" void kernel_launch(void* const* d_in, const int* in_sizes, int n_in,
                              void* d_out, int out_size, void* d_ws, size_t ws_size,
                              hipStream_t stream) {
    const float* x   = (const float*)d_in[0];
    const float* mem = (const float*)d_in[1];
    float* mT        = (float*)d_ws;                    // 64*4096 floats = 1 MB
    float* out_read  = (float*)d_out;                   // [32768*64]
    float* out_w     = out_read + (long)NROWS * HD;     // [32768*4096]

    prep_m<<<NM / 4, 256, 0, stream>>>(mem, mT);
    prep_x<<<NROWS / 4, 256, 0, stream>>>(x, out_read); // x-hat parked in out_read
    sgemm_logits<<<dim3(NM / 128, NROWS / 128), 256, 0, stream>>>(out_read, mT, out_w);
    finish<<<NROWS / 4, 256, 0, stream>>>(out_w, mem, out_read);
}

// Round 3
// 807.478 us; speedup vs baseline: 5.2012x; 1.0807x over previous
//
#include <hip/hip_runtime.h>
#include <hip/hip_bf16.h>

// Round 3: logits GEMM moved to bf16 MFMA (16x16x32), no LDS, no transpose.
//   prep_rows : L2-normalize rows, scale, convert to bf16 [row][64]
//               (x -> xb with scale=2 (1/T folded), memories -> mb, scale=1)
//   mfma_logits: logits[32768][4096] -> out_w region, fp32.
//               Block = 16 rows (A-frag pair hoisted), 4 waves split N.
//   finish    : per-row softmax + hard-shrink + L1 renorm + sparse read-GEMM
//               (unchanged — measured near its 1.08 GB HBM floor).
// bf16 logits error ~4e-3 absolute; shrink threshold needs ~1.5 logit shift
// to matter -> outputs unchanged.

#define NM 4096
#define HD 64
#define NROWS 32768  // 16*2048

typedef short bf16x8 __attribute__((ext_vector_type(8)));
typedef float f32x4  __attribute__((ext_vector_type(4)));

// ---- prep: normalized rows -> bf16 [row][k], scale folded in ----
__global__ __launch_bounds__(256) void prep_rows(const float* __restrict__ src,
                                                 ushort* __restrict__ dst,
                                                 float scale) {
    const int wave = threadIdx.x >> 6, lane = threadIdx.x & 63;
    const long row = (long)blockIdx.x * 4 + wave;
    float v = src[row * HD + lane];
    float s = v * v;
#pragma unroll
    for (int o = 32; o; o >>= 1) s += __shfl_xor(s, o, 64);
    const float inv = scale / fmaxf(sqrtf(s), 1e-12f);
    __hip_bfloat16 h = __float2bfloat16(v * inv);
    dst[row * HD + lane] = *reinterpret_cast<ushort*>(&h);
}

// ---- K1: logits via MFMA.  Grid = NROWS/16 blocks of 4 waves. ----
// A-frag: lane holds xb[m0 + (lane&15)][q*8 .. q*8+7], q = lane>>4 (16 B load).
// B-frag: lane holds mb[n0 + (lane&15)][q*8 .. q*8+7].
// C/D   : col = lane&15, row = q*4 + reg  [verified layout, learn_hip m89].
__global__ __launch_bounds__(256) void mfma_logits(const ushort* __restrict__ xb,
                                                   const ushort* __restrict__ mb,
                                                   float* __restrict__ out_w) {
    const int wv = threadIdx.x >> 6, lane = threadIdx.x & 63;
    const int q = lane >> 4, c = lane & 15;
    const int m0 = blockIdx.x * 16;

    const bf16x8 a0 = *(const bf16x8*)(xb + (long)(m0 + c) * HD + q * 8);
    const bf16x8 a1 = *(const bf16x8*)(xb + (long)(m0 + c) * HD + q * 8 + 32);

    float* wbase = out_w + (long)(m0 + q * 4) * NM;

#pragma unroll 4
    for (int i = 0; i < 64; i++) {
        const int n0 = wv * 1024 + i * 16;
        const bf16x8 b0 = *(const bf16x8*)(mb + (long)(n0 + c) * HD + q * 8);
        const bf16x8 b1 = *(const bf16x8*)(mb + (long)(n0 + c) * HD + q * 8 + 32);
        f32x4 acc = {0.0f, 0.0f, 0.0f, 0.0f};
        acc = __builtin_amdgcn_mfma_f32_16x16x32_bf16(a0, b0, acc, 0, 0, 0);
        acc = __builtin_amdgcn_mfma_f32_16x16x32_bf16(a1, b1, acc, 0, 0, 0);
#pragma unroll
        for (int r = 0; r < 4; r++)
            wbase[(long)r * NM + n0 + c] = acc[r];
    }
}

// ---- K2: softmax + hard_shrink_relu + L1 renorm + sparse read-GEMM ----
__global__ __launch_bounds__(256) void finish(float* __restrict__ out_w,
                                              const float* __restrict__ mem,
                                              float* __restrict__ out_read) {
    const int wave = threadIdx.x >> 6, lane = threadIdx.x & 63;
    const long row = (long)blockIdx.x * 4 + wave;
    float* wrow = out_w + row * (long)NM;

    // lane owns memories {c*256 + 4*lane .. +3}, c = 0..15
    float4 lw[16];
#pragma unroll
    for (int c = 0; c < 16; c++)
        lw[c] = *(const float4*)(wrow + c * 256 + lane * 4);

    float mx = -1e30f;
#pragma unroll
    for (int c = 0; c < 16; c++)
        mx = fmaxf(mx, fmaxf(fmaxf(lw[c].x, lw[c].y), fmaxf(lw[c].z, lw[c].w)));
#pragma unroll
    for (int o = 32; o; o >>= 1) mx = fmaxf(mx, __shfl_xor(mx, o, 64));

    float se = 0.0f;
#pragma unroll
    for (int c = 0; c < 16; c++) {
        lw[c].x = __expf(lw[c].x - mx); se += lw[c].x;
        lw[c].y = __expf(lw[c].y - mx); se += lw[c].y;
        lw[c].z = __expf(lw[c].z - mx); se += lw[c].z;
        lw[c].w = __expf(lw[c].w - mx); se += lw[c].w;
    }
#pragma unroll
    for (int o = 32; o; o >>= 1) se += __shfl_xor(se, o, 64);
    const float rS = 1.0f / se;

    float l1 = 0.0f;
#pragma unroll
    for (int c = 0; c < 16; c++) {
        float* e = &lw[c].x;
#pragma unroll
        for (int q = 0; q < 4; q++) {
            float w  = e[q] * rS;
            float d  = w - 0.0025f;
            float sh = __fdividef(fmaxf(d, 0.0f) * w, fabsf(d) + 1e-12f);
            e[q] = sh;
            l1  += sh;
        }
    }
#pragma unroll
    for (int o = 32; o; o >>= 1) l1 += __shfl_xor(l1, o, 64);
    const float rL = 1.0f / fmaxf(l1, 1e-12f);

    float racc = 0.0f;
#pragma unroll
    for (int c = 0; c < 16; c++) {
        float4 wv;
        wv.x = lw[c].x * rL; wv.y = lw[c].y * rL;
        wv.z = lw[c].z * rL; wv.w = lw[c].w * rL;
        *(float4*)(wrow + c * 256 + lane * 4) = wv;

        // sparse read-GEMM: wave-uniform skip of all-zero lanes
        const bool nz = (wv.x != 0.0f) | (wv.y != 0.0f) |
                        (wv.z != 0.0f) | (wv.w != 0.0f);
        unsigned long long mask = __ballot(nz);
        while (mask) {
            const int j = __ffsll((long long)mask) - 1;
            mask &= (mask - 1);
            float w0 = __shfl(wv.x, j, 64), w1 = __shfl(wv.y, j, 64);
            float w2 = __shfl(wv.z, j, 64), w3 = __shfl(wv.w, j, 64);
            const long mbase = (long)(c * 256 + 4 * j) * HD + lane;
            racc = fmaf(w0, mem[mbase + 0 * HD], racc);
            racc = fmaf(w1, mem[mbase + 1 * HD], racc);
            racc = fmaf(w2, mem[mbase + 2 * HD], racc);
            racc = fmaf(w3, mem[mbase + 3 * HD], racc);
        }
    }
    out_read[row * HD + lane] = racc;
}

extern "C" void kernel_launch(void* const* d_in, const int* in_sizes, int n_in,
                              void* d_out, int out_size, void* d_ws, size_t ws_size,
                              hipStream_t stream) {
    const float* x   = (const float*)d_in[0];
    const float* mem = (const float*)d_in[1];
    ushort* xb       = (ushort*)d_ws;                 // 32768*64 bf16 = 4 MB
    ushort* mb       = xb + (long)NROWS * HD;         // 4096*64 bf16 = 512 KB
    float* out_read  = (float*)d_out;                 // [32768*64]
    float* out_w     = out_read + (long)NROWS * HD;   // [32768*4096]

    prep_rows<<<NROWS / 4, 256, 0, stream>>>(x, xb, 2.0f);   // 1/T folded
    prep_rows<<<NM / 4, 256, 0, stream>>>(mem, mb, 1.0f);
    mfma_logits<<<NROWS / 16, 256, 0, stream>>>(xb, mb, out_w);
    finish<<<NROWS / 4, 256, 0, stream>>>(out_w, mem, out_read);
}

// Round 4
// 776.162 us; speedup vs baseline: 5.4111x; 1.0403x over previous
//
#include <hip/hip_runtime.h>
#include <hip/hip_bf16.h>

// Round 4: single fused kernel — logits MFMA + softmax + hard-shrink + L1
// renorm + sparse read-GEMM, weights written to HBM exactly once.
//   prep_rows : L2-normalize rows -> bf16 [row][64] (x scaled by 2 = 1/T)
//   fused_mem : block = 16 x-rows; 4 waves x 1024-col strips.
//               Logit tile [16][4096] lives in registers (f32x4 acc[64]/lane,
//               ~300 VGPR, __launch_bounds__(256,1)).  Row stats via
//               shfl_xor over 16-lane col groups + small-LDS cross-wave
//               combine.  Final sweep: scale, store weights (only write),
//               ballot-sparse read accumulation (mem rows L2-resident).
// Weight-region HBM traffic: 1.6 GB (R3) -> 537 MB.

#define NM 4096
#define HD 64
#define NROWS 32768  // 16*2048

typedef short bf16x8 __attribute__((ext_vector_type(8)));
typedef float f32x4  __attribute__((ext_vector_type(4)));

// ---- prep: normalized rows -> bf16 [row][k], scale folded in ----
__global__ __launch_bounds__(256) void prep_rows(const float* __restrict__ src,
                                                 ushort* __restrict__ dst,
                                                 float scale) {
    const int wave = threadIdx.x >> 6, lane = threadIdx.x & 63;
    const long row = (long)blockIdx.x * 4 + wave;
    float v = src[row * HD + lane];
    float s = v * v;
#pragma unroll
    for (int o = 32; o; o >>= 1) s += __shfl_xor(s, o, 64);
    const float inv = scale / fmaxf(sqrtf(s), 1e-12f);
    __hip_bfloat16 h = __float2bfloat16(v * inv);
    dst[row * HD + lane] = *reinterpret_cast<ushort*>(&h);
}

// A-frag: lane holds xb[m0+(lane&15)][q*8..+7], q=lane>>4.  B-frag same on mb.
// C/D: col = lane&15, row = q*4 + reg   [verified layout, learn_hip m89/m91].
__global__ __launch_bounds__(256, 1) void fused_mem(const ushort* __restrict__ xb,
                                                    const ushort* __restrict__ mb,
                                                    const float* __restrict__ mem,
                                                    float* __restrict__ out_w,
                                                    float* __restrict__ out_read) {
    const int wv = threadIdx.x >> 6, lane = threadIdx.x & 63;
    const int q = lane >> 4, c = lane & 15;
    const int m0 = blockIdx.x * 16;
    const int nbase = wv * 1024;

    __shared__ float smax[4][16];
    __shared__ float ssum[4][16];
    __shared__ float sl1[4][16];
    __shared__ float sred[4][16][64];  // read partials, 16 KB

    const bf16x8 a0 = *(const bf16x8*)(xb + (long)(m0 + c) * HD + q * 8);
    const bf16x8 a1 = *(const bf16x8*)(xb + (long)(m0 + c) * HD + q * 8 + 32);

    // ---- logits for this wave's 1024-col strip: 256 floats/lane ----
    f32x4 acc[64];
#pragma unroll
    for (int i = 0; i < 64; i++) {
        const int n0 = nbase + i * 16;
        const bf16x8 b0 = *(const bf16x8*)(mb + (long)(n0 + c) * HD + q * 8);
        const bf16x8 b1 = *(const bf16x8*)(mb + (long)(n0 + c) * HD + q * 8 + 32);
        f32x4 t = {0.0f, 0.0f, 0.0f, 0.0f};
        t = __builtin_amdgcn_mfma_f32_16x16x32_bf16(a0, b0, t, 0, 0, 0);
        t = __builtin_amdgcn_mfma_f32_16x16x32_bf16(a1, b1, t, 0, 0, 0);
        acc[i] = t;
    }

    // ---- row max (strip -> 16-lane group -> cross-wave) ----
    float mx[4] = {-1e30f, -1e30f, -1e30f, -1e30f};
#pragma unroll
    for (int i = 0; i < 64; i++)
#pragma unroll
        for (int r = 0; r < 4; r++) mx[r] = fmaxf(mx[r], acc[i][r]);
#pragma unroll
    for (int o = 1; o < 16; o <<= 1)
#pragma unroll
        for (int r = 0; r < 4; r++) mx[r] = fmaxf(mx[r], __shfl_xor(mx[r], o, 64));
    if (c == 0)
#pragma unroll
        for (int r = 0; r < 4; r++) smax[wv][q * 4 + r] = mx[r];
    __syncthreads();
    float gm[4];
#pragma unroll
    for (int r = 0; r < 4; r++)
        gm[r] = fmaxf(fmaxf(smax[0][q * 4 + r], smax[1][q * 4 + r]),
                      fmaxf(smax[2][q * 4 + r], smax[3][q * 4 + r]));

    // ---- exp + row sum ----
    float sm[4] = {0.0f, 0.0f, 0.0f, 0.0f};
#pragma unroll
    for (int i = 0; i < 64; i++)
#pragma unroll
        for (int r = 0; r < 4; r++) {
            float e = __expf(acc[i][r] - gm[r]);
            acc[i][r] = e;
            sm[r] += e;
        }
#pragma unroll
    for (int o = 1; o < 16; o <<= 1)
#pragma unroll
        for (int r = 0; r < 4; r++) sm[r] += __shfl_xor(sm[r], o, 64);
    if (c == 0)
#pragma unroll
        for (int r = 0; r < 4; r++) ssum[wv][q * 4 + r] = sm[r];
    __syncthreads();
    float rS[4];
#pragma unroll
    for (int r = 0; r < 4; r++)
        rS[r] = 1.0f / (ssum[0][q * 4 + r] + ssum[1][q * 4 + r] +
                        ssum[2][q * 4 + r] + ssum[3][q * 4 + r]);

    // ---- hard_shrink_relu + L1 ----
    float l1[4] = {0.0f, 0.0f, 0.0f, 0.0f};
#pragma unroll
    for (int i = 0; i < 64; i++)
#pragma unroll
        for (int r = 0; r < 4; r++) {
            float w  = acc[i][r] * rS[r];
            float d  = w - 0.0025f;
            float sh = __fdividef(fmaxf(d, 0.0f) * w, fabsf(d) + 1e-12f);
            acc[i][r] = sh;
            l1[r] += sh;
        }
#pragma unroll
    for (int o = 1; o < 16; o <<= 1)
#pragma unroll
        for (int r = 0; r < 4; r++) l1[r] += __shfl_xor(l1[r], o, 64);
    if (c == 0)
#pragma unroll
        for (int r = 0; r < 4; r++) sl1[wv][q * 4 + r] = l1[r];
    __syncthreads();
    float rL[4];
#pragma unroll
    for (int r = 0; r < 4; r++)
        rL[r] = 1.0f / fmaxf(sl1[0][q * 4 + r] + sl1[1][q * 4 + r] +
                             sl1[2][q * 4 + r] + sl1[3][q * 4 + r], 1e-12f);

    // ---- scale + single weight store + ballot-sparse read accum ----
    float racc[16];
#pragma unroll
    for (int r = 0; r < 16; r++) racc[r] = 0.0f;
    float* wbase = out_w + (long)(m0 + q * 4) * NM + c;
#pragma unroll
    for (int i = 0; i < 64; i++) {
        const int n0 = nbase + i * 16;
        float w0 = acc[i][0] * rL[0], w1 = acc[i][1] * rL[1];
        float w2 = acc[i][2] * rL[2], w3 = acc[i][3] * rL[3];
        wbase[0L * NM + n0] = w0;
        wbase[1L * NM + n0] = w1;
        wbase[2L * NM + n0] = w2;
        wbase[3L * NM + n0] = w3;

        const bool nz = (w0 != 0.0f) | (w1 != 0.0f) | (w2 != 0.0f) | (w3 != 0.0f);
        unsigned long long mask = __ballot(nz);
        while (mask) {
            const int j = __ffsll((long long)mask) - 1;
            mask &= (mask - 1);
            const int qj = j >> 4, cj = j & 15;
            float b0 = __shfl(w0, j, 64), b1 = __shfl(w1, j, 64);
            float b2 = __shfl(w2, j, 64), b3 = __shfl(w3, j, 64);
            const float mv = mem[(long)(n0 + cj) * HD + lane];
            switch (qj) {  // wave-uniform branch
                case 0: racc[0]  += b0 * mv; racc[1]  += b1 * mv;
                        racc[2]  += b2 * mv; racc[3]  += b3 * mv; break;
                case 1: racc[4]  += b0 * mv; racc[5]  += b1 * mv;
                        racc[6]  += b2 * mv; racc[7]  += b3 * mv; break;
                case 2: racc[8]  += b0 * mv; racc[9]  += b1 * mv;
                        racc[10] += b2 * mv; racc[11] += b3 * mv; break;
                default: racc[12] += b0 * mv; racc[13] += b1 * mv;
                         racc[14] += b2 * mv; racc[15] += b3 * mv; break;
            }
        }
    }

    // ---- combine read partials across waves, store ----
#pragma unroll
    for (int r = 0; r < 16; r++) sred[wv][r][lane] = racc[r];
    __syncthreads();
#pragma unroll
    for (int rr = 0; rr < 4; rr++) {
        const int row = wv * 4 + rr;
        const float v = sred[0][row][lane] + sred[1][row][lane] +
                        sred[2][row][lane] + sred[3][row][lane];
        out_read[(long)(m0 + row) * HD + lane] = v;
    }
}

extern "C" void kernel_launch(void* const* d_in, const int* in_sizes, int n_in,
                              void* d_out, int out_size, void* d_ws, size_t ws_size,
                              hipStream_t stream) {
    const float* x   = (const float*)d_in[0];
    const float* mem = (const float*)d_in[1];
    ushort* xb       = (ushort*)d_ws;                 // 32768*64 bf16 = 4 MB
    ushort* mb       = xb + (long)NROWS * HD;         // 4096*64 bf16 = 512 KB
    float* out_read  = (float*)d_out;                 // [32768*64]
    float* out_w     = out_read + (long)NROWS * HD;   // [32768*4096]

    prep_rows<<<NROWS / 4, 256, 0, stream>>>(x, xb, 2.0f);  // 1/T folded
    prep_rows<<<NM / 4, 256, 0, stream>>>(mem, mb, 1.0f);
    fused_mem<<<NROWS / 16, 256, 0, stream>>>(xb, mb, mem, out_w, out_read);
}